// Round 11
// baseline (376.441 us; speedup 1.0000x reference)
//
#include <hip/hip_runtime.h>

typedef unsigned short u16;
typedef float f32x4 __attribute__((ext_vector_type(4)));
typedef __bf16 bf16x8 __attribute__((ext_vector_type(8)));
typedef u16 u16x8 __attribute__((ext_vector_type(8)));

#define VMCNT(n) asm volatile("s_waitcnt vmcnt(" #n ")" ::: "memory")

static __device__ __forceinline__ u16 f2bf(float f) {
  union { float f; unsigned u; } v; v.f = f;
  unsigned r = v.u + 0x7fffu + ((v.u >> 16) & 1u);  // RNE
  return (u16)(r >> 16);
}
static __device__ __forceinline__ float bf2f(u16 x) {
  union { unsigned u; float f; } v; v.u = (unsigned)x << 16; return v.f;
}

static __device__ __forceinline__ f32x4 mfma16(u16x8 a, u16x8 b, f32x4 c) {
  return __builtin_amdgcn_mfma_f32_16x16x32_bf16(
      __builtin_bit_cast(bf16x8, a), __builtin_bit_cast(bf16x8, b), c, 0, 0, 0);
}

static __device__ __forceinline__ void load_lds16(const void* g, void* l) {
  __builtin_amdgcn_global_load_lds(
      (const __attribute__((address_space(1))) void*)g,
      (__attribute__((address_space(3))) void*)l, 16, 0, 0);
}

// ---------------- f32 -> bf16, GEMM-A pre-swizzled (chunk c of row r at c^(r&7)) ----
__global__ void cvt_f32_bf16_swz(const float* __restrict__ in, u16* __restrict__ out, int n8) {
  int i = blockIdx.x * blockDim.x + threadIdx.x;
  if (i >= n8) return;
  int row = i >> 9;
  int j = i & 511;
  int jp = (j & ~7) | ((j & 7) ^ (row & 7));
  const float* src = in + (size_t)i * 8;
  u16x8 o;
  #pragma unroll
  for (int e = 0; e < 8; e++) o[e] = f2bf(src[e]);
  *(u16x8*)(out + ((size_t)row << 12) + jp * 8) = o;
}

// ------- transpose + convert: W[K][N] f32 -> Wt[N][K] bf16, pre-swizzled rows -------
__global__ __launch_bounds__(256)
void transpose_cvt(const float* __restrict__ W, u16* __restrict__ Wt, int K, int N) {
  __shared__ float tile[128][33];
  const int k0 = blockIdx.x * 128, n0 = blockIdx.y * 32;
  const int tr = threadIdx.x >> 3;         // 0..31
  const int tc4 = (threadIdx.x & 7) * 4;   // 0..28
  #pragma unroll
  for (int it = 0; it < 4; it++) {
    int kl = it * 32 + tr;
    float4 v = *(const float4*)&W[(size_t)(k0 + kl) * N + n0 + tc4];
    tile[kl][tc4] = v.x; tile[kl][tc4 + 1] = v.y;
    tile[kl][tc4 + 2] = v.z; tile[kl][tc4 + 3] = v.w;
  }
  __syncthreads();
  const int nl = threadIdx.x >> 4;         // 0..15
  const int dch = threadIdx.x & 15;        // dest 16B chunk 0..15
  #pragma unroll
  for (int it = 0; it < 2; it++) {
    int n = n0 + it * 16 + nl;
    int sch = (dch & 8) | ((dch & 7) ^ (n & 7));  // source chunk (involution)
    u16x8 o;
    #pragma unroll
    for (int e = 0; e < 8; e++) o[e] = f2bf(tile[sch * 8 + e][it * 16 + nl]);
    *(u16x8*)&Wt[(size_t)n * K + k0 + dch * 8] = o;
  }
}

// ---------------- RoPE cos/sin table: [L][64] float2 ----------------
__global__ void rope_table_k(float2* __restrict__ tab, const int* __restrict__ start, int L) {
  int i = blockIdx.x * blockDim.x + threadIdx.x;
  if (i >= L * 64) return;
  int p = i >> 6, j = i & 63;
  float inv = powf(10000.0f, -(float)j / 64.0f);
  float ang = (float)(p + start[0]) * inv;
  tab[i] = make_float2(cosf(ang), sinf(ang));
}

// ---------------- RoPE apply (bf16 in, strided) -> bf16 [L][H][128], * scale ----------
__global__ void rope_apply_b(const u16* __restrict__ in, int istride, int icol,
                             u16* __restrict__ outp, const float2* __restrict__ tab,
                             int total, int H, float scale, int swz) {
  int i = blockIdx.x * blockDim.x + threadIdx.x;  // total = L*H*8
  if (i >= total) return;
  int j8 = (i & 7) * 8;
  int h = (i >> 3) % H;
  int p = i / (8 * H);
  const u16* base = in + (size_t)p * istride + icol + h * 128;
  u16x8 a = *(const u16x8*)(base + j8);
  u16x8 b = *(const u16x8*)(base + j8 + 64);
  u16x8 o1, o2;
  #pragma unroll
  for (int e = 0; e < 8; e++) {
    float2 cs = tab[p * 64 + j8 + e];
    float av = bf2f(a[e]), bv = bf2f(b[e]);
    o1[e] = f2bf((av * cs.x - bv * cs.y) * scale);
    o2[e] = f2bf((av * cs.y + bv * cs.x) * scale);
  }
  int c1 = i & 7;
  int cs1 = swz ? (c1 ^ (p & 7)) : c1;
  u16* ob = outp + ((size_t)p * H + h) * 128 + cs1 * 8;
  *(u16x8*)ob = o1;
  *(u16x8*)(ob + 64) = o2;
}

// ======== 8-phase GEMM: C = A[M][K] @ Bt[N][K]; BM=256, BK=64, 512 thr (2x4 waves) ==
// Burst staging + 2 free gates (R10 structure, B-READ FORMULA FIXED): all loads of
// tile 2i+1 issue at p0-p1 (->buf1), tile 2i+2 at p4-p5 (->buf0); gates ONLY at
// end-p3 / end-p7 (vmcnt(0) on loads 2-3 phases old ~2000-3600cy >> HBM latency ->
// never stalls). Soundness: all of tile t's loads retire at the gate BEFORE the
// barrier that precedes t's first read (per-wave vmcnt + shared barrier). WAR:
// each buffer's last read is >=2 barriers before its re-staging. B LDS layout is
// LINEAR (LDS row = global row offset); fragment read row MUST mirror the epilogue
// column map: R = wcn*(16*N_REP) + n2*(16*NHALF) + ni*16 + ql  [R10 bug: used the
// old stripe-layout formula -> wrong B rows]. row&7 preserved -> chunk-XOR reads
// conflict-free (2 lanes/slot).
template<int BN, bool OUT_BF16>
__global__ __launch_bounds__(512, 2)
void gemm8p(const u16* __restrict__ A, const u16* __restrict__ Bt,
            float* __restrict__ Cf, u16* __restrict__ Cb, int N, int K, int gm) {
  constexpr int N_REP = BN / 64;
  constexpr int NHALF = N_REP / 2 > 0 ? N_REP / 2 : 1;
  __shared__ alignas(16) u16 As[2][256 * 64];
  __shared__ alignas(16) u16 Bs[2][BN * 64];
  const int tid = threadIdx.x;
  const int lane = tid & 63;
  const int wid = tid >> 6;
  const int ql = lane & 15, kg = lane >> 4;
  const int wr = wid >> 2, wcn = wid & 3;

  const int nb = gridDim.x;
  const int b = blockIdx.x;
  const int swz = (b & 7) * (nb >> 3) + (b >> 3);
  const int m0 = (swz % gm) * 256;
  const int n0 = (swz / gm) * BN;

  const int srow = tid >> 3, schk = tid & 7;
  const u16* abase = A + (size_t)(m0 + srow) * K + schk * 8;
  const u16* bbase = Bt + (size_t)(n0 + srow) * K + schk * 8;

  // region = 64 consecutive rows; one block-wide load (512 thr x 16B) covers it
  auto stageA = [&](int buf, int t, int qa) {
    load_lds16(abase + (size_t)(qa * 64) * K + t * 64,
               &As[buf][((qa * 64 + srow) * 8 + schk) * 8]);
  };
  auto stageB = [&](int buf, int t, int rb) {
    load_lds16(bbase + (size_t)(rb * 64) * K + t * 64,
               &Bs[buf][((rb * 64 + srow) * 8 + schk) * 8]);
  };

  f32x4 acc[8][N_REP] = {};
  u16x8 af[4][2];
  u16x8 bfr[2][NHALF][2];
  const int NT = K / 64;

  // prologue: tile 0 -> buf0, gate, barrier
  stageA(0, 0, 0); stageA(0, 0, 2);
  #pragma unroll
  for (int rb = 0; rb < N_REP; rb++) stageB(0, 0, rb);
  stageA(0, 0, 1); stageA(0, 0, 3);
  VMCNT(0);
  __builtin_amdgcn_sched_barrier(0);
  __builtin_amdgcn_s_barrier();

  #pragma unroll 1
  for (int i = 0; i < NT / 2; i++) {
    #pragma unroll
    for (int p = 0; p < 8; p++) {
      const int q = p & 3;
      const int m = q >> 1, n2 = q & 1;
      const int cbuf = (p < 4) ? 0 : 1;
      // ds_reads for this quadrant (data published by the previous barrier)
      if (q == 0 || q == 2) {
        #pragma unroll
        for (int mi = 0; mi < 4; mi++)
          #pragma unroll
          for (int kk = 0; kk < 2; kk++) {
            int row = wr * 128 + m * 64 + mi * 16 + ql;
            int ch = ((kk << 2) | kg) ^ (ql & 7);
            af[mi][kk] = *(const u16x8*)&As[cbuf][(row * 8 + ch) * 8];
          }
      }
      if (q == 0 || q == 1) {
        #pragma unroll
        for (int ni = 0; ni < NHALF; ni++)
          #pragma unroll
          for (int kk = 0; kk < 2; kk++) {
            // LINEAR layout: LDS row == global row offset == C-column offset
            int R = wcn * (16 * N_REP) + n2 * (16 * NHALF) + ni * 16 + ql;
            int ch = ((kk << 2) | kg) ^ (ql & 7);
            bfr[n2][ni][kk] = *(const u16x8*)&Bs[cbuf][(R * 8 + ch) * 8];
          }
      }
      // BURST staging: tile 2i+1 at p0/p1 (->buf1), tile 2i+2 at p4/p5 (->buf0)
      const int st = 2 * i + 1 + (p >= 4 ? 1 : 0);
      const int sbuf = st & 1;
      if (st < NT) {
        if (q == 0) {
          stageA(sbuf, st, 0); stageA(sbuf, st, 2);
          #pragma unroll
          for (int rb = 0; rb < N_REP / 2; rb++) stageB(sbuf, st, rb);
        } else if (q == 1) {
          #pragma unroll
          for (int rb = N_REP / 2; rb < N_REP; rb++) stageB(sbuf, st, rb);
          stageA(sbuf, st, 1); stageA(sbuf, st, 3);
        }
      }
      // gates: only end-p3 / end-p7; loads are 2-3 phases old -> no stall
      if (q == 3) VMCNT(0);
      __builtin_amdgcn_sched_barrier(0);
      __builtin_amdgcn_s_barrier();
      asm volatile("s_waitcnt lgkmcnt(0)" ::: "memory");
      __builtin_amdgcn_sched_barrier(0);
      __builtin_amdgcn_s_setprio(1);
      #pragma unroll
      for (int mi = 0; mi < 4; mi++)
        #pragma unroll
        for (int ni = 0; ni < NHALF; ni++)
          #pragma unroll
          for (int kk = 0; kk < 2; kk++)
            acc[m * 4 + mi][n2 * NHALF + ni] =
                mfma16(af[mi][kk], bfr[n2][ni][kk], acc[m * 4 + mi][n2 * NHALF + ni]);
      __builtin_amdgcn_s_setprio(0);
      __builtin_amdgcn_sched_barrier(0);
      __builtin_amdgcn_s_barrier();
    }
  }

  #pragma unroll
  for (int mi = 0; mi < 8; mi++) {
    #pragma unroll
    for (int ni = 0; ni < N_REP; ni++) {
      int row0 = m0 + wr * 128 + mi * 16 + kg * 4;
      int col = n0 + wcn * (16 * N_REP) + ni * 16 + ql;
      #pragma unroll
      for (int r = 0; r < 4; r++) {
        if constexpr (OUT_BF16)
          Cb[(size_t)(row0 + r) * N + col] = f2bf(acc[mi][ni][r]);
        else
          Cf[(size_t)(row0 + r) * N + col] = acc[mi][ni][r];
      }
    }
  }
}

// ---------------- flash attention, causal, GQA (g=4) ----------------
// (unchanged from R9)
__global__ __launch_bounds__(256, 2)
void attn_k(const u16* __restrict__ qr, const u16* __restrict__ kr,
            const u16* __restrict__ qkv, u16* __restrict__ out) {
  __shared__ alignas(16) u16 Kls[2][64 * 128];
  __shared__ alignas(16) u16 Vt[2][128][72];
  __shared__ alignas(16) u16 Plds[4][16][72];
  const int tid = threadIdx.x;
  const int lane = tid & 63, wave = tid >> 6;
  const int ql = lane & 15, kg = lane >> 4;
  const int h = blockIdx.y, hk = h >> 2;

  const int sl4 = (tid & 15) * 4;
  const int d0s = (tid >> 4) * 8;
  const u16* vbase = qkv + 5120 + (size_t)hk * 128 + d0s;
  const int krow_s = tid >> 4, kcol_s = (tid & 15) * 8;
  const u16* kbase = kr + (size_t)hk * 128 + (size_t)krow_s * 1024 + kcol_s;

  int cur = 0;
  #pragma unroll 1
  for (int half_idx = 0; half_idx < 2; half_idx++) {
    const int tile = half_idx ? (31 - (int)blockIdx.x) : (int)blockIdx.x;
    const int q0 = tile * 64;
    const int qw = q0 + wave * 16;
    const int nsteps = tile + 1;

    u16x8 qf[4];
    const u16* qbase = qr + ((size_t)(qw + ql) * 32 + h) * 128;
    #pragma unroll
    for (int kk = 0; kk < 4; kk++)
      qf[kk] = *(const u16x8*)(qbase + kk * 32 + kg * 8);

    f32x4 acc[8] = {};
    float m_run = -3e38f, l_run = 0.f;

    __syncthreads();
    cur = 0;
    #pragma unroll
    for (int r = 0; r < 4; r++)
      load_lds16(kbase + (size_t)r * 16 * 1024, &Kls[0][(r * 256 + tid) * 8]);
    u16x8 vreg[4];
    #pragma unroll
    for (int j = 0; j < 4; j++)
      vreg[j] = *(const u16x8*)(vbase + (size_t)(sl4 + j) * 6144);

    #pragma unroll 1
    for (int t = 0; t < nsteps; t++) {
      const int s0 = t * 64;
      #pragma unroll
      for (int e = 0; e < 8; e++) {
        ushort4 w;
        w.x = vreg[0][e]; w.y = vreg[1][e]; w.z = vreg[2][e]; w.w = vreg[3][e];
        *(ushort4*)&Vt[cur][d0s + e][sl4] = w;
      }
      __syncthreads();  // the ONLY barrier per step
      if (t + 1 < nsteps) {
        const u16* kn = kbase + (size_t)(s0 + 64) * 1024;
        #pragma unroll
        for (int r = 0; r < 4; r++)
          load_lds16(kn + (size_t)r * 16 * 1024, &Kls[cur ^ 1][(r * 256 + tid) * 8]);
        #pragma unroll
        for (int j = 0; j < 4; j++)
          vreg[j] = *(const u16x8*)(vbase + (size_t)(s0 + 64 + sl4 + j) * 6144);
      }
      f32x4 sc[4] = {};
      __builtin_amdgcn_s_setprio(1);
      #pragma unroll
      for (int sb = 0; sb < 4; sb++) {
        const u16* krow = &Kls[cur][(sb * 16 + ql) * 128];
        #pragma unroll
        for (int kk = 0; kk < 4; kk++) {
          u16x8 kf = *(const u16x8*)(krow + (((kk * 4 + kg) ^ (ql & 7)) * 8));
          sc[sb] = mfma16(kf, qf[kk], sc[sb]);
        }
      }
      __builtin_amdgcn_s_setprio(0);
      const int qg = qw + ql;
      float mt = -3e38f;
      #pragma unroll
      for (int sb = 0; sb < 4; sb++)
        #pragma unroll
        for (int r = 0; r < 4; r++) {
          int s = s0 + sb * 16 + kg * 4 + r;
          float v = (s > qg) ? -3e38f : sc[sb][r];
          sc[sb][r] = v;
          mt = fmaxf(mt, v);
        }
      mt = fmaxf(mt, __shfl_xor(mt, 16, 64));
      mt = fmaxf(mt, __shfl_xor(mt, 32, 64));
      if (!__all(mt - m_run <= 11.5f)) {
        float m_new = fmaxf(m_run, mt);
        float fco = exp2f(m_run - m_new);
        float fr[4];
        #pragma unroll
        for (int r = 0; r < 4; r++) fr[r] = __shfl(fco, (lane & 48) | (kg * 4 + r), 64);
        #pragma unroll
        for (int db = 0; db < 8; db++)
          #pragma unroll
          for (int r = 0; r < 4; r++) acc[db][r] *= fr[r];
        l_run *= fco;
        m_run = m_new;
      }
      float rs = 0.f;
      #pragma unroll
      for (int sb = 0; sb < 4; sb++)
        #pragma unroll
        for (int r = 0; r < 4; r++) {
          float e = exp2f(sc[sb][r] - m_run);
          sc[sb][r] = e;
          rs += e;
        }
      rs += __shfl_xor(rs, 16, 64);
      rs += __shfl_xor(rs, 32, 64);
      l_run += rs;
      #pragma unroll
      for (int sb = 0; sb < 4; sb++) {
        ushort4 pk;
        pk.x = f2bf(sc[sb][0]); pk.y = f2bf(sc[sb][1]);
        pk.z = f2bf(sc[sb][2]); pk.w = f2bf(sc[sb][3]);
        *(ushort4*)&Plds[wave][ql][sb * 16 + kg * 4] = pk;
      }
      __builtin_amdgcn_s_setprio(1);
      #pragma unroll
      for (int hf = 0; hf < 2; hf++) {
        u16x8 pf = *(const u16x8*)&Plds[wave][ql][hf * 32 + kg * 8];
        #pragma unroll
        for (int db = 0; db < 8; db++) {
          u16x8 vf = *(const u16x8*)&Vt[cur][db * 16 + ql][hf * 32 + kg * 8];
          acc[db] = mfma16(pf, vf, acc[db]);
        }
      }
      __builtin_amdgcn_s_setprio(0);
      cur ^= 1;
    }

    float linv[4];
    #pragma unroll
    for (int r = 0; r < 4; r++)
      linv[r] = 1.f / __shfl(l_run, (lane & 48) | (kg * 4 + r), 64);
    #pragma unroll
    for (int db = 0; db < 8; db++) {
      int d = db * 16 + ql;
      #pragma unroll
      for (int r = 0; r < 4; r++) {
        int q = qw + kg * 4 + r;
        int col = (h * 128 + d) ^ ((q & 7) << 3);
        out[(size_t)q * 4096 + col] = f2bf(acc[db][r] * linv[r]);
      }
    }
  }
}

// ---------------- launcher ----------------
extern "C" void kernel_launch(void* const* d_in, const int* in_sizes, int n_in,
                              void* d_out, int out_size, void* d_ws, size_t ws_size,
                              hipStream_t stream) {
  const float* x  = (const float*)d_in[0];
  const float* Wq = (const float*)d_in[1];
  const float* Wk = (const float*)d_in[2];
  const float* Wv = (const float*)d_in[3];
  const float* Wo = (const float*)d_in[4];
  const int* start = (const int*)d_in[5];

  const int L = 2048, HID = 4096, NH = 32, NKV = 8;
  const int NQ = 4096, NKVD = 1024, NF = 6144;

  char* ws = (char*)d_ws;
  size_t off = 0;
  auto alloc = [&](size_t bytes) {
    void* p = ws + off;
    off += (bytes + 255) & ~(size_t)255;
    return p;
  };
  u16* x_b   = (u16*)alloc((size_t)L * HID * 2);
  // Wq_t, Wk_t, Wv_t MUST be contiguous (fused GEMM reads them as one 6144-row Bt).
  u16* Wq_t  = (u16*)alloc((size_t)NQ * HID * 2);
  u16* Wk_t  = (u16*)alloc((size_t)NKVD * HID * 2);
  u16* Wv_t  = (u16*)alloc((size_t)NKVD * HID * 2);
  u16* Wo_t  = (u16*)alloc((size_t)HID * NQ * 2);
  u16* q_r   = (u16*)alloc((size_t)L * NQ * 2);
  u16* k_r   = (u16*)alloc((size_t)L * NKVD * 2);
  float2* tab = (float2*)alloc((size_t)L * 64 * sizeof(float2));
  u16* qkv_b  = (u16*)d_out;   // fused QKV output; fully rewritten by out-proj
  u16* attn_b = Wq_t;          // reuse Wq^T region after the fused GEMM

  const float qscale = 0.08838834764831845f * 1.4426950408889634f;  // 1/sqrt(128)*log2(e)

  // conversions / transposes / table (all GEMM inputs pre-swizzled)
  cvt_f32_bf16_swz<<<(L * HID / 8 + 255) / 256, 256, 0, stream>>>(x, x_b, L * HID / 8);
  transpose_cvt<<<dim3(HID / 128, NQ / 32), 256, 0, stream>>>(Wq, Wq_t, HID, NQ);
  transpose_cvt<<<dim3(HID / 128, NKVD / 32), 256, 0, stream>>>(Wk, Wk_t, HID, NKVD);
  transpose_cvt<<<dim3(HID / 128, NKVD / 32), 256, 0, stream>>>(Wv, Wv_t, HID, NKVD);
  transpose_cvt<<<dim3(NQ / 128, HID / 32), 256, 0, stream>>>(Wo, Wo_t, NQ, HID);
  rope_table_k<<<(L * 64 + 255) / 256, 256, 0, stream>>>(tab, start, L);

  // fused QKV projection: [2048][6144] bf16 (8-phase, 256x256 tiles, grid 192)
  gemm8p<256, true><<<192, 512, 0, stream>>>(x_b, Wq_t, nullptr, qkv_b, NF, HID, 8);

  // RoPE: Q (scaled, log2e folded, linear) and K (unscaled, chunk-swizzled)
  rope_apply_b<<<(L * NH * 8 + 255) / 256, 256, 0, stream>>>(qkv_b, NF, 0, q_r, tab, L * NH * 8, NH, qscale, 0);
  rope_apply_b<<<(L * NKV * 8 + 255) / 256, 256, 0, stream>>>(qkv_b, NF, NQ, k_r, tab, L * NKV * 8, NKV, 1.0f, 1);

  // attention
  attn_k<<<dim3(16, NH), 256, 0, stream>>>(q_r, k_r, qkv_b, attn_b);

  // output projection: 8-phase, 256x128 tiles, grid 256 (1 block/CU)
  gemm8p<128, false><<<256, 512, 0, stream>>>(attn_b, Wo_t, (float*)d_out, nullptr, HID, NQ, 8);
}

// Round 12
// 366.646 us; speedup vs baseline: 1.0267x; 1.0267x over previous
//
#include <hip/hip_runtime.h>

typedef unsigned short u16;
typedef float f32x4 __attribute__((ext_vector_type(4)));
typedef __bf16 bf16x8 __attribute__((ext_vector_type(8)));
typedef u16 u16x8 __attribute__((ext_vector_type(8)));

#define VMCNT(n) asm volatile("s_waitcnt vmcnt(" #n ")" ::: "memory")

static __device__ __forceinline__ u16 f2bf(float f) {
  union { float f; unsigned u; } v; v.f = f;
  unsigned r = v.u + 0x7fffu + ((v.u >> 16) & 1u);  // RNE
  return (u16)(r >> 16);
}
static __device__ __forceinline__ float bf2f(u16 x) {
  union { unsigned u; float f; } v; v.u = (unsigned)x << 16; return v.f;
}

static __device__ __forceinline__ f32x4 mfma16(u16x8 a, u16x8 b, f32x4 c) {
  return __builtin_amdgcn_mfma_f32_16x16x32_bf16(
      __builtin_bit_cast(bf16x8, a), __builtin_bit_cast(bf16x8, b), c, 0, 0, 0);
}

static __device__ __forceinline__ void load_lds16(const void* g, void* l) {
  __builtin_amdgcn_global_load_lds(
      (const __attribute__((address_space(1))) void*)g,
      (__attribute__((address_space(3))) void*)l, 16, 0, 0);
}

// ---------------- f32 -> bf16, GEMM-A pre-swizzled (chunk c of row r at c^(r&7)) ----
__global__ void cvt_f32_bf16_swz(const float* __restrict__ in, u16* __restrict__ out, int n8) {
  int i = blockIdx.x * blockDim.x + threadIdx.x;
  if (i >= n8) return;
  int row = i >> 9;
  int j = i & 511;
  int jp = (j & ~7) | ((j & 7) ^ (row & 7));
  const float* src = in + (size_t)i * 8;
  u16x8 o;
  #pragma unroll
  for (int e = 0; e < 8; e++) o[e] = f2bf(src[e]);
  *(u16x8*)(out + ((size_t)row << 12) + jp * 8) = o;
}

// ------- transpose + convert: W[K][N] f32 -> Wt[N][K] bf16, pre-swizzled rows -------
__global__ __launch_bounds__(256)
void transpose_cvt(const float* __restrict__ W, u16* __restrict__ Wt, int K, int N) {
  __shared__ float tile[128][33];
  const int k0 = blockIdx.x * 128, n0 = blockIdx.y * 32;
  const int tr = threadIdx.x >> 3;         // 0..31
  const int tc4 = (threadIdx.x & 7) * 4;   // 0..28
  #pragma unroll
  for (int it = 0; it < 4; it++) {
    int kl = it * 32 + tr;
    float4 v = *(const float4*)&W[(size_t)(k0 + kl) * N + n0 + tc4];
    tile[kl][tc4] = v.x; tile[kl][tc4 + 1] = v.y;
    tile[kl][tc4 + 2] = v.z; tile[kl][tc4 + 3] = v.w;
  }
  __syncthreads();
  const int nl = threadIdx.x >> 4;         // 0..15
  const int dch = threadIdx.x & 15;        // dest 16B chunk 0..15
  #pragma unroll
  for (int it = 0; it < 2; it++) {
    int n = n0 + it * 16 + nl;
    int sch = (dch & 8) | ((dch & 7) ^ (n & 7));  // source chunk (involution)
    u16x8 o;
    #pragma unroll
    for (int e = 0; e < 8; e++) o[e] = f2bf(tile[sch * 8 + e][it * 16 + nl]);
    *(u16x8*)&Wt[(size_t)n * K + k0 + dch * 8] = o;
  }
}

// ---------------- RoPE cos/sin table: [L][64] float2 ----------------
__global__ void rope_table_k(float2* __restrict__ tab, const int* __restrict__ start, int L) {
  int i = blockIdx.x * blockDim.x + threadIdx.x;
  if (i >= L * 64) return;
  int p = i >> 6, j = i & 63;
  float inv = powf(10000.0f, -(float)j / 64.0f);
  float ang = (float)(p + start[0]) * inv;
  tab[i] = make_float2(cosf(ang), sinf(ang));
}

// ---------------- RoPE apply (bf16 in, strided) -> bf16 [L][H][128], * scale ----------
__global__ void rope_apply_b(const u16* __restrict__ in, int istride, int icol,
                             u16* __restrict__ outp, const float2* __restrict__ tab,
                             int total, int H, float scale, int swz) {
  int i = blockIdx.x * blockDim.x + threadIdx.x;  // total = L*H*8
  if (i >= total) return;
  int j8 = (i & 7) * 8;
  int h = (i >> 3) % H;
  int p = i / (8 * H);
  const u16* base = in + (size_t)p * istride + icol + h * 128;
  u16x8 a = *(const u16x8*)(base + j8);
  u16x8 b = *(const u16x8*)(base + j8 + 64);
  u16x8 o1, o2;
  #pragma unroll
  for (int e = 0; e < 8; e++) {
    float2 cs = tab[p * 64 + j8 + e];
    float av = bf2f(a[e]), bv = bf2f(b[e]);
    o1[e] = f2bf((av * cs.x - bv * cs.y) * scale);
    o2[e] = f2bf((av * cs.y + bv * cs.x) * scale);
  }
  int c1 = i & 7;
  int cs1 = swz ? (c1 ^ (p & 7)) : c1;
  u16* ob = outp + ((size_t)p * H + h) * 128 + cs1 * 8;
  *(u16x8*)ob = o1;
  *(u16x8*)(ob + 64) = o2;
}

// ======== 8-phase GEMM: C = A[M][K] @ Bt[N][K]; BM=256, BK=64, 512 thr (2x4 waves) ==
// m201-TRUE PIPELINE: uniform stage units (A-half = 2 loads of 64 rows; B-full =
// N_REP loads), placed so every load is >=4 phases old at its first read:
//   p0: A-m1(2i+1)  p1: B(2i+1)  p2: A-m0(2i+2)  p3: -
//   p4: A-m1(2i+2)  p5: B(2i+2)  p6: A-m0(2i+3)  p7: -
// Gates ONLY at end-p3 / end-p7: vmcnt(2) (leaves just the phase-2/-6 A-half in
// flight). RAW: end-p3 retires through p1 -> covers all p4-p7 reads (A-m0(2i+1)
// staged prev-p6, B(2i+1) p1, A-m1(2i+1) p0); end-p7 retires through p5 ->
// covers next-iter p0-p3 reads (A-m0 p2, B p5, A-m1 p4). WAR: every stage lands
// >=1 barrier after its slot's last ds_read (A-m1 slot read p2/p3 <- staged p4;
// B slot last ds_read p1/p5 <- staged p5/p1-next; A-m0 read p0/p1 <- staged p2;
// all checked per-unit). Tail iter: gates become vmcnt(0) (loads >=2 phases old,
// one-time). Reads never wait on loads <4 phases old -> phases decouple from HBM
// latency (fixes R9); no drain-0 on fresh loads (fixes R11). B LDS layout LINEAR,
// read row R = wcn*(16*N_REP) + n2*(16*NHALF) + ni*16 + ql (R11-verified).
// row&7 preserved everywhere -> chunk-XOR ds_reads conflict-free.
template<int BN, bool OUT_BF16>
__global__ __launch_bounds__(512, 2)
void gemm8p(const u16* __restrict__ A, const u16* __restrict__ Bt,
            float* __restrict__ Cf, u16* __restrict__ Cb, int N, int K, int gm) {
  constexpr int N_REP = BN / 64;
  constexpr int NHALF = N_REP / 2 > 0 ? N_REP / 2 : 1;
  __shared__ alignas(16) u16 As[2][256 * 64];
  __shared__ alignas(16) u16 Bs[2][BN * 64];
  const int tid = threadIdx.x;
  const int lane = tid & 63;
  const int wid = tid >> 6;
  const int ql = lane & 15, kg = lane >> 4;
  const int wr = wid >> 2, wcn = wid & 3;

  const int nb = gridDim.x;
  const int b = blockIdx.x;
  const int swz = (b & 7) * (nb >> 3) + (b >> 3);
  const int m0 = (swz % gm) * 256;
  const int n0 = (swz / gm) * BN;

  const int srow = tid >> 3, schk = tid & 7;
  const u16* abase = A + (size_t)(m0 + srow) * K + schk * 8;
  const u16* bbase = Bt + (size_t)(n0 + srow) * K + schk * 8;

  // stage units: A-half = rows [half*128, half*128+128) = 2 block-wide loads;
  // B-full = all BN rows = N_REP loads. LDS row = global row offset (linear).
  auto stageA = [&](int buf, int t, int half) {
    #pragma unroll
    for (int r = 0; r < 2; r++) {
      int reg = half * 2 + r;
      load_lds16(abase + (size_t)(reg * 64) * K + t * 64,
                 &As[buf][((reg * 64 + srow) * 8 + schk) * 8]);
    }
  };
  auto stageB = [&](int buf, int t) {
    #pragma unroll
    for (int rb = 0; rb < N_REP; rb++)
      load_lds16(bbase + (size_t)(rb * 64) * K + t * 64,
                 &Bs[buf][((rb * 64 + srow) * 8 + schk) * 8]);
  };

  f32x4 acc[8][N_REP] = {};
  u16x8 af[4][2];
  u16x8 bfr[2][NHALF][2];
  const int NT = K / 64;

  // prologue: tile0 fully (buf0) + tile1's A-m0 (buf1); drain once; barrier.
  stageA(0, 0, 0); stageA(0, 0, 1); stageB(0, 0);
  stageA(1, 1, 0);
  VMCNT(0);
  __builtin_amdgcn_sched_barrier(0);
  __builtin_amdgcn_s_barrier();

  #pragma unroll 1
  for (int i = 0; i < NT / 2; i++) {
    const bool tail = (i == NT / 2 - 1);
    const int t1 = 2 * i + 1, t2 = 2 * i + 2, t3 = 2 * i + 3;
    #pragma unroll
    for (int p = 0; p < 8; p++) {
      const int q = p & 3;
      const int m = q >> 1, n2 = q & 1;
      const int cbuf = (p < 4) ? 0 : 1;
      // ds_reads for this quadrant (published by an earlier gate+barrier)
      if (q == 0 || q == 2) {
        #pragma unroll
        for (int mi = 0; mi < 4; mi++)
          #pragma unroll
          for (int kk = 0; kk < 2; kk++) {
            int row = wr * 128 + m * 64 + mi * 16 + ql;
            int ch = ((kk << 2) | kg) ^ (ql & 7);
            af[mi][kk] = *(const u16x8*)&As[cbuf][(row * 8 + ch) * 8];
          }
      }
      if (q == 0 || q == 1) {
        #pragma unroll
        for (int ni = 0; ni < NHALF; ni++)
          #pragma unroll
          for (int kk = 0; kk < 2; kk++) {
            int R = wcn * (16 * N_REP) + n2 * (16 * NHALF) + ni * 16 + ql;
            int ch = ((kk << 2) | kg) ^ (ql & 7);
            bfr[n2][ni][kk] = *(const u16x8*)&Bs[cbuf][(R * 8 + ch) * 8];
          }
      }
      // uniform stage units (see header schedule)
      if (p == 0)      stageA(1, t1, 1);
      else if (p == 1) stageB(1, t1);
      else if (p == 2) { if (t2 < NT) stageA(0, t2, 0); }
      else if (p == 4) { if (t2 < NT) stageA(0, t2, 1); }
      else if (p == 5) { if (t2 < NT) stageB(0, t2); }
      else if (p == 6) { if (t3 < NT) stageA(1, t3, 0); }
      // counted gates, two per iter; tail drains (loads >=2 phases old)
      if (p == 3 || p == 7) {
        if (tail) VMCNT(0); else VMCNT(2);
      }
      __builtin_amdgcn_sched_barrier(0);
      __builtin_amdgcn_s_barrier();
      asm volatile("s_waitcnt lgkmcnt(0)" ::: "memory");
      __builtin_amdgcn_sched_barrier(0);
      __builtin_amdgcn_s_setprio(1);
      #pragma unroll
      for (int mi = 0; mi < 4; mi++)
        #pragma unroll
        for (int ni = 0; ni < NHALF; ni++)
          #pragma unroll
          for (int kk = 0; kk < 2; kk++)
            acc[m * 4 + mi][n2 * NHALF + ni] =
                mfma16(af[mi][kk], bfr[n2][ni][kk], acc[m * 4 + mi][n2 * NHALF + ni]);
      __builtin_amdgcn_s_setprio(0);
      __builtin_amdgcn_sched_barrier(0);
      __builtin_amdgcn_s_barrier();
    }
  }

  #pragma unroll
  for (int mi = 0; mi < 8; mi++) {
    #pragma unroll
    for (int ni = 0; ni < N_REP; ni++) {
      int row0 = m0 + wr * 128 + mi * 16 + kg * 4;
      int col = n0 + wcn * (16 * N_REP) + ni * 16 + ql;
      #pragma unroll
      for (int r = 0; r < 4; r++) {
        if constexpr (OUT_BF16)
          Cb[(size_t)(row0 + r) * N + col] = f2bf(acc[mi][ni][r]);
        else
          Cf[(size_t)(row0 + r) * N + col] = acc[mi][ni][r];
      }
    }
  }
}

// ---------------- flash attention, causal, GQA (g=4) ----------------
// (unchanged from R9/R11)
__global__ __launch_bounds__(256, 2)
void attn_k(const u16* __restrict__ qr, const u16* __restrict__ kr,
            const u16* __restrict__ qkv, u16* __restrict__ out) {
  __shared__ alignas(16) u16 Kls[2][64 * 128];
  __shared__ alignas(16) u16 Vt[2][128][72];
  __shared__ alignas(16) u16 Plds[4][16][72];
  const int tid = threadIdx.x;
  const int lane = tid & 63, wave = tid >> 6;
  const int ql = lane & 15, kg = lane >> 4;
  const int h = blockIdx.y, hk = h >> 2;

  const int sl4 = (tid & 15) * 4;
  const int d0s = (tid >> 4) * 8;
  const u16* vbase = qkv + 5120 + (size_t)hk * 128 + d0s;
  const int krow_s = tid >> 4, kcol_s = (tid & 15) * 8;
  const u16* kbase = kr + (size_t)hk * 128 + (size_t)krow_s * 1024 + kcol_s;

  int cur = 0;
  #pragma unroll 1
  for (int half_idx = 0; half_idx < 2; half_idx++) {
    const int tile = half_idx ? (31 - (int)blockIdx.x) : (int)blockIdx.x;
    const int q0 = tile * 64;
    const int qw = q0 + wave * 16;
    const int nsteps = tile + 1;

    u16x8 qf[4];
    const u16* qbase = qr + ((size_t)(qw + ql) * 32 + h) * 128;
    #pragma unroll
    for (int kk = 0; kk < 4; kk++)
      qf[kk] = *(const u16x8*)(qbase + kk * 32 + kg * 8);

    f32x4 acc[8] = {};
    float m_run = -3e38f, l_run = 0.f;

    __syncthreads();
    cur = 0;
    #pragma unroll
    for (int r = 0; r < 4; r++)
      load_lds16(kbase + (size_t)r * 16 * 1024, &Kls[0][(r * 256 + tid) * 8]);
    u16x8 vreg[4];
    #pragma unroll
    for (int j = 0; j < 4; j++)
      vreg[j] = *(const u16x8*)(vbase + (size_t)(sl4 + j) * 6144);

    #pragma unroll 1
    for (int t = 0; t < nsteps; t++) {
      const int s0 = t * 64;
      #pragma unroll
      for (int e = 0; e < 8; e++) {
        ushort4 w;
        w.x = vreg[0][e]; w.y = vreg[1][e]; w.z = vreg[2][e]; w.w = vreg[3][e];
        *(ushort4*)&Vt[cur][d0s + e][sl4] = w;
      }
      __syncthreads();  // the ONLY barrier per step
      if (t + 1 < nsteps) {
        const u16* kn = kbase + (size_t)(s0 + 64) * 1024;
        #pragma unroll
        for (int r = 0; r < 4; r++)
          load_lds16(kn + (size_t)r * 16 * 1024, &Kls[cur ^ 1][(r * 256 + tid) * 8]);
        #pragma unroll
        for (int j = 0; j < 4; j++)
          vreg[j] = *(const u16x8*)(vbase + (size_t)(s0 + 64 + sl4 + j) * 6144);
      }
      f32x4 sc[4] = {};
      __builtin_amdgcn_s_setprio(1);
      #pragma unroll
      for (int sb = 0; sb < 4; sb++) {
        const u16* krow = &Kls[cur][(sb * 16 + ql) * 128];
        #pragma unroll
        for (int kk = 0; kk < 4; kk++) {
          u16x8 kf = *(const u16x8*)(krow + (((kk * 4 + kg) ^ (ql & 7)) * 8));
          sc[sb] = mfma16(kf, qf[kk], sc[sb]);
        }
      }
      __builtin_amdgcn_s_setprio(0);
      const int qg = qw + ql;
      float mt = -3e38f;
      #pragma unroll
      for (int sb = 0; sb < 4; sb++)
        #pragma unroll
        for (int r = 0; r < 4; r++) {
          int s = s0 + sb * 16 + kg * 4 + r;
          float v = (s > qg) ? -3e38f : sc[sb][r];
          sc[sb][r] = v;
          mt = fmaxf(mt, v);
        }
      mt = fmaxf(mt, __shfl_xor(mt, 16, 64));
      mt = fmaxf(mt, __shfl_xor(mt, 32, 64));
      if (!__all(mt - m_run <= 11.5f)) {
        float m_new = fmaxf(m_run, mt);
        float fco = exp2f(m_run - m_new);
        float fr[4];
        #pragma unroll
        for (int r = 0; r < 4; r++) fr[r] = __shfl(fco, (lane & 48) | (kg * 4 + r), 64);
        #pragma unroll
        for (int db = 0; db < 8; db++)
          #pragma unroll
          for (int r = 0; r < 4; r++) acc[db][r] *= fr[r];
        l_run *= fco;
        m_run = m_new;
      }
      float rs = 0.f;
      #pragma unroll
      for (int sb = 0; sb < 4; sb++)
        #pragma unroll
        for (int r = 0; r < 4; r++) {
          float e = exp2f(sc[sb][r] - m_run);
          sc[sb][r] = e;
          rs += e;
        }
      rs += __shfl_xor(rs, 16, 64);
      rs += __shfl_xor(rs, 32, 64);
      l_run += rs;
      #pragma unroll
      for (int sb = 0; sb < 4; sb++) {
        ushort4 pk;
        pk.x = f2bf(sc[sb][0]); pk.y = f2bf(sc[sb][1]);
        pk.z = f2bf(sc[sb][2]); pk.w = f2bf(sc[sb][3]);
        *(ushort4*)&Plds[wave][ql][sb * 16 + kg * 4] = pk;
      }
      __builtin_amdgcn_s_setprio(1);
      #pragma unroll
      for (int hf = 0; hf < 2; hf++) {
        u16x8 pf = *(const u16x8*)&Plds[wave][ql][hf * 32 + kg * 8];
        #pragma unroll
        for (int db = 0; db < 8; db++) {
          u16x8 vf = *(const u16x8*)&Vt[cur][db * 16 + ql][hf * 32 + kg * 8];
          acc[db] = mfma16(pf, vf, acc[db]);
        }
      }
      __builtin_amdgcn_s_setprio(0);
      cur ^= 1;
    }

    float linv[4];
    #pragma unroll
    for (int r = 0; r < 4; r++)
      linv[r] = 1.f / __shfl(l_run, (lane & 48) | (kg * 4 + r), 64);
    #pragma unroll
    for (int db = 0; db < 8; db++) {
      int d = db * 16 + ql;
      #pragma unroll
      for (int r = 0; r < 4; r++) {
        int q = qw + kg * 4 + r;
        int col = (h * 128 + d) ^ ((q & 7) << 3);
        out[(size_t)q * 4096 + col] = f2bf(acc[db][r] * linv[r]);
      }
    }
  }
}

// ---------------- launcher ----------------
extern "C" void kernel_launch(void* const* d_in, const int* in_sizes, int n_in,
                              void* d_out, int out_size, void* d_ws, size_t ws_size,
                              hipStream_t stream) {
  const float* x  = (const float*)d_in[0];
  const float* Wq = (const float*)d_in[1];
  const float* Wk = (const float*)d_in[2];
  const float* Wv = (const float*)d_in[3];
  const float* Wo = (const float*)d_in[4];
  const int* start = (const int*)d_in[5];

  const int L = 2048, HID = 4096, NH = 32, NKV = 8;
  const int NQ = 4096, NKVD = 1024, NF = 6144;

  char* ws = (char*)d_ws;
  size_t off = 0;
  auto alloc = [&](size_t bytes) {
    void* p = ws + off;
    off += (bytes + 255) & ~(size_t)255;
    return p;
  };
  u16* x_b   = (u16*)alloc((size_t)L * HID * 2);
  // Wq_t, Wk_t, Wv_t MUST be contiguous (fused GEMM reads them as one 6144-row Bt).
  u16* Wq_t  = (u16*)alloc((size_t)NQ * HID * 2);
  u16* Wk_t  = (u16*)alloc((size_t)NKVD * HID * 2);
  u16* Wv_t  = (u16*)alloc((size_t)NKVD * HID * 2);
  u16* Wo_t  = (u16*)alloc((size_t)HID * NQ * 2);
  u16* q_r   = (u16*)alloc((size_t)L * NQ * 2);
  u16* k_r   = (u16*)alloc((size_t)L * NKVD * 2);
  float2* tab = (float2*)alloc((size_t)L * 64 * sizeof(float2));
  u16* qkv_b  = (u16*)d_out;   // fused QKV output; fully rewritten by out-proj
  u16* attn_b = Wq_t;          // reuse Wq^T region after the fused GEMM

  const float qscale = 0.08838834764831845f * 1.4426950408889634f;  // 1/sqrt(128)*log2(e)

  // conversions / transposes / table (all GEMM inputs pre-swizzled)
  cvt_f32_bf16_swz<<<(L * HID / 8 + 255) / 256, 256, 0, stream>>>(x, x_b, L * HID / 8);
  transpose_cvt<<<dim3(HID / 128, NQ / 32), 256, 0, stream>>>(Wq, Wq_t, HID, NQ);
  transpose_cvt<<<dim3(HID / 128, NKVD / 32), 256, 0, stream>>>(Wk, Wk_t, HID, NKVD);
  transpose_cvt<<<dim3(HID / 128, NKVD / 32), 256, 0, stream>>>(Wv, Wv_t, HID, NKVD);
  transpose_cvt<<<dim3(NQ / 128, HID / 32), 256, 0, stream>>>(Wo, Wo_t, NQ, HID);
  rope_table_k<<<(L * 64 + 255) / 256, 256, 0, stream>>>(tab, start, L);

  // fused QKV projection: [2048][6144] bf16 (8-phase, 256x256 tiles, grid 192)
  gemm8p<256, true><<<192, 512, 0, stream>>>(x_b, Wq_t, nullptr, qkv_b, NF, HID, 8);

  // RoPE: Q (scaled, log2e folded, linear) and K (unscaled, chunk-swizzled)
  rope_apply_b<<<(L * NH * 8 + 255) / 256, 256, 0, stream>>>(qkv_b, NF, 0, q_r, tab, L * NH * 8, NH, qscale, 0);
  rope_apply_b<<<(L * NKV * 8 + 255) / 256, 256, 0, stream>>>(qkv_b, NF, NQ, k_r, tab, L * NKV * 8, NKV, 1.0f, 1);

  // attention
  attn_k<<<dim3(16, NH), 256, 0, stream>>>(q_r, k_r, qkv_b, attn_b);

  // output projection: 8-phase, 256x128 tiles, grid 256 (1 block/CU)
  gemm8p<128, false><<<256, 512, 0, stream>>>(attn_b, Wo_t, (float*)d_out, nullptr, HID, NQ, 8);
}

// Round 13
// 325.266 us; speedup vs baseline: 1.1573x; 1.1272x over previous
//
#include <hip/hip_runtime.h>

typedef unsigned short u16;
typedef float f32x4 __attribute__((ext_vector_type(4)));
typedef __bf16 bf16x8 __attribute__((ext_vector_type(8)));
typedef u16 u16x8 __attribute__((ext_vector_type(8)));

#define VMCNT(n) asm volatile("s_waitcnt vmcnt(" #n ")" ::: "memory")

static __device__ __forceinline__ u16 f2bf(float f) {
  union { float f; unsigned u; } v; v.f = f;
  unsigned r = v.u + 0x7fffu + ((v.u >> 16) & 1u);  // RNE
  return (u16)(r >> 16);
}
static __device__ __forceinline__ float bf2f(u16 x) {
  union { unsigned u; float f; } v; v.u = (unsigned)x << 16; return v.f;
}

static __device__ __forceinline__ f32x4 mfma16(u16x8 a, u16x8 b, f32x4 c) {
  return __builtin_amdgcn_mfma_f32_16x16x32_bf16(
      __builtin_bit_cast(bf16x8, a), __builtin_bit_cast(bf16x8, b), c, 0, 0, 0);
}

static __device__ __forceinline__ void load_lds16(const void* g, void* l) {
  __builtin_amdgcn_global_load_lds(
      (const __attribute__((address_space(1))) void*)g,
      (__attribute__((address_space(3))) void*)l, 16, 0, 0);
}

// ---------------- f32 -> bf16, GEMM-A pre-swizzled (chunk c of row r at c^(r&7)) ----
__global__ void cvt_f32_bf16_swz(const float* __restrict__ in, u16* __restrict__ out, int n8) {
  int i = blockIdx.x * blockDim.x + threadIdx.x;
  if (i >= n8) return;
  int row = i >> 9;
  int j = i & 511;
  int jp = (j & ~7) | ((j & 7) ^ (row & 7));
  const float* src = in + (size_t)i * 8;
  u16x8 o;
  #pragma unroll
  for (int e = 0; e < 8; e++) o[e] = f2bf(src[e]);
  *(u16x8*)(out + ((size_t)row << 12) + jp * 8) = o;
}

// ------- transpose + convert: W[K][N] f32 -> Wt[N][K] bf16, pre-swizzled rows -------
__global__ __launch_bounds__(256)
void transpose_cvt(const float* __restrict__ W, u16* __restrict__ Wt, int K, int N) {
  __shared__ float tile[128][33];
  const int k0 = blockIdx.x * 128, n0 = blockIdx.y * 32;
  const int tr = threadIdx.x >> 3;         // 0..31
  const int tc4 = (threadIdx.x & 7) * 4;   // 0..28
  #pragma unroll
  for (int it = 0; it < 4; it++) {
    int kl = it * 32 + tr;
    float4 v = *(const float4*)&W[(size_t)(k0 + kl) * N + n0 + tc4];
    tile[kl][tc4] = v.x; tile[kl][tc4 + 1] = v.y;
    tile[kl][tc4 + 2] = v.z; tile[kl][tc4 + 3] = v.w;
  }
  __syncthreads();
  const int nl = threadIdx.x >> 4;         // 0..15
  const int dch = threadIdx.x & 15;        // dest 16B chunk 0..15
  #pragma unroll
  for (int it = 0; it < 2; it++) {
    int n = n0 + it * 16 + nl;
    int sch = (dch & 8) | ((dch & 7) ^ (n & 7));  // source chunk (involution)
    u16x8 o;
    #pragma unroll
    for (int e = 0; e < 8; e++) o[e] = f2bf(tile[sch * 8 + e][it * 16 + nl]);
    *(u16x8*)&Wt[(size_t)n * K + k0 + dch * 8] = o;
  }
}

// ---------------- RoPE cos/sin table: [L][64] float2 ----------------
__global__ void rope_table_k(float2* __restrict__ tab, const int* __restrict__ start, int L) {
  int i = blockIdx.x * blockDim.x + threadIdx.x;
  if (i >= L * 64) return;
  int p = i >> 6, j = i & 63;
  float inv = powf(10000.0f, -(float)j / 64.0f);
  float ang = (float)(p + start[0]) * inv;
  tab[i] = make_float2(cosf(ang), sinf(ang));
}

// ---------------- RoPE apply (bf16 in, strided) -> bf16 [L][H][128], * scale ----------
__global__ void rope_apply_b(const u16* __restrict__ in, int istride, int icol,
                             u16* __restrict__ outp, const float2* __restrict__ tab,
                             int total, int H, float scale, int swz) {
  int i = blockIdx.x * blockDim.x + threadIdx.x;  // total = L*H*8
  if (i >= total) return;
  int j8 = (i & 7) * 8;
  int h = (i >> 3) % H;
  int p = i / (8 * H);
  const u16* base = in + (size_t)p * istride + icol + h * 128;
  u16x8 a = *(const u16x8*)(base + j8);
  u16x8 b = *(const u16x8*)(base + j8 + 64);
  u16x8 o1, o2;
  #pragma unroll
  for (int e = 0; e < 8; e++) {
    float2 cs = tab[p * 64 + j8 + e];
    float av = bf2f(a[e]), bv = bf2f(b[e]);
    o1[e] = f2bf((av * cs.x - bv * cs.y) * scale);
    o2[e] = f2bf((av * cs.y + bv * cs.x) * scale);
  }
  int c1 = i & 7;
  int cs1 = swz ? (c1 ^ (p & 7)) : c1;
  u16* ob = outp + ((size_t)p * H + h) * 128 + cs1 * 8;
  *(u16x8*)ob = o1;
  *(u16x8*)(ob + 64) = o2;
}

// ======== 8-phase GEMM, 2 BLOCKS/CU: C = A[M][K] @ Bt[N][K]; BM=128, 256 thr ========
// 4 waves (2x2), wave-tile 64 x (BN/2). Two blocks co-reside per CU (LDS 80KB for
// BN=192, 64KB for BN=128) -> each block's barriers sync only its own 4 waves; the
// sibling block's waves fill barrier/stall gaps (the 1-block/CU configs R7-R12 all
// pinned at ~1250cy/phase regardless of gate scheme -> CU-idle at barriers was the
// residual). Quadrant phases (m,n2) = (0,0),(0,1),(1,0),(1,1); reads at phase top:
// q0: A-mh0 + B-nh0, q1: B-nh1, q2: A-mh1, q3: none (regs held: af = current A-half,
// bfr = both B-halves). Staging (32-row calls; A:4, B:6 or 4 per K-tile) spread over
// p0-p3 (tile 2i+1 -> buf1) / p4-p7 (tile 2i+2 -> buf0), scheduled so every call
// retires >= 1 gate+barrier before its first read (full per-call RAW audit, incl.
// iteration boundary; end-of-phase sliding gates vmcnt(issued(p)+issued(p-1)) ==
// R9's proven-sound rule). WAR: stage issues after the barrier that closes the
// buffer's last read phase. Chunk-XOR reads (row&7 preserved) -> 0 bank conflicts.
template<int BN, bool OUT_BF16>
__global__ __launch_bounds__(256, 2)
void gemm8p(const u16* __restrict__ A, const u16* __restrict__ Bt,
            float* __restrict__ Cf, u16* __restrict__ Cb, int N, int K, int gm) {
  constexpr int N_REP = BN / 32;        // 6 (BN=192) or 4 (BN=128)
  constexpr int NHALF = N_REP / 2;      // 3 or 2
  __shared__ alignas(16) u16 As[2][128 * 64];
  __shared__ alignas(16) u16 Bs[2][BN * 64];
  const int tid = threadIdx.x;
  const int lane = tid & 63;
  const int wid = tid >> 6;
  const int ql = lane & 15, kg = lane >> 4;
  const int wr = wid >> 1, wcn = wid & 1;

  const int nb = gridDim.x;
  const int b = blockIdx.x;
  const int swz = (b & 7) * (nb >> 3) + (b >> 3);
  const int m0 = (swz % gm) * 128;
  const int n0 = (swz / gm) * BN;

  const int srow = tid >> 3, schk = tid & 7;   // 32 rows x 8 chunks per call
  const u16* abase = A + (size_t)(m0 + srow) * K + schk * 8;
  const u16* bbase = Bt + (size_t)(n0 + srow) * K + schk * 8;

  auto stA = [&](int buf, int t, int c) {
    load_lds16(abase + (size_t)(c * 32) * K + t * 64,
               &As[buf][((c * 32 + srow) * 8 + schk) * 8]);
  };
  auto stB = [&](int buf, int t, int c) {
    load_lds16(bbase + (size_t)(c * 32) * K + t * 64,
               &Bs[buf][((c * 32 + srow) * 8 + schk) * 8]);
  };

  f32x4 acc[4][N_REP] = {};
  u16x8 af[2][2];            // current A-half: 2 frags x 2 k-slices
  u16x8 bfr[2][NHALF][2];    // both B-halves
  const int NT = K / 64;

  // prologue: tile 0 -> buf0 fully; drain; barrier
  stA(0, 0, 0); stA(0, 0, 1); stA(0, 0, 2); stA(0, 0, 3);
  #pragma unroll
  for (int c = 0; c < BN / 32; c++) stB(0, 0, c);
  VMCNT(0);
  __builtin_amdgcn_sched_barrier(0);
  __builtin_amdgcn_s_barrier();

  #pragma unroll 1
  for (int i = 0; i < NT / 2; i++) {
    const bool tail = (i == NT / 2 - 1);
    #pragma unroll
    for (int p = 0; p < 8; p++) {
      const int q = p & 3;
      const int m = q >> 1, n2 = q & 1;
      const int cbuf = (p < 4) ? 0 : 1;
      // ds_reads for this quadrant
      if (q == 0 || q == 2) {
        #pragma unroll
        for (int mi = 0; mi < 2; mi++)
          #pragma unroll
          for (int kk = 0; kk < 2; kk++) {
            int row = wr * 64 + m * 32 + mi * 16 + ql;
            int ch = ((kk << 2) | kg) ^ (ql & 7);
            af[mi][kk] = *(const u16x8*)&As[cbuf][(row * 8 + ch) * 8];
          }
      }
      if (q == 0 || q == 1) {
        #pragma unroll
        for (int ni = 0; ni < NHALF; ni++)
          #pragma unroll
          for (int kk = 0; kk < 2; kk++) {
            int R = wcn * (16 * N_REP) + n2 * (16 * NHALF) + ni * 16 + ql;
            int ch = ((kk << 2) | kg) ^ (ql & 7);
            bfr[n2][ni][kk] = *(const u16x8*)&Bs[cbuf][(R * 8 + ch) * 8];
          }
      }
      // staging: tile 2i+1 at p0-3 (->buf1), tile 2i+2 at p4-7 (->buf0)
      const int st = 2 * i + 1 + (p >= 4 ? 1 : 0);
      const int sbuf = st & 1;
      if (st < NT) {
        if constexpr (BN == 192) {
          if (q == 0) { stA(sbuf, st, 0); stA(sbuf, st, 2); stB(sbuf, st, 0); }
          else if (q == 1) { stB(sbuf, st, 1); stB(sbuf, st, 3); stB(sbuf, st, 4); }
          else if (q == 2) { stB(sbuf, st, 2); stB(sbuf, st, 5); }
          else { stA(sbuf, st, 1); stA(sbuf, st, 3); }
        } else {
          if (q == 0) { stA(sbuf, st, 0); stA(sbuf, st, 2); stB(sbuf, st, 0); }
          else if (q == 1) { stB(sbuf, st, 2); stB(sbuf, st, 1); }
          else if (q == 2) { stB(sbuf, st, 3); }
          else { stA(sbuf, st, 1); stA(sbuf, st, 3); }
        }
      }
      // end-of-phase sliding gates: vmcnt(issued(p) + issued(p-1))
      if (!tail || p < 4) {
        if constexpr (BN == 192) {
          if (q == 1) VMCNT(6);
          else if (q == 3) VMCNT(4);
          else VMCNT(5);
        } else {
          if (q == 0 || q == 1) VMCNT(5);
          else VMCNT(3);
        }
      } else {
        if (p == 4) VMCNT(2);
        else VMCNT(0);  // nothing outstanding; free
      }
      __builtin_amdgcn_sched_barrier(0);
      __builtin_amdgcn_s_barrier();
      asm volatile("s_waitcnt lgkmcnt(0)" ::: "memory");
      __builtin_amdgcn_sched_barrier(0);
      __builtin_amdgcn_s_setprio(1);
      #pragma unroll
      for (int mi = 0; mi < 2; mi++)
        #pragma unroll
        for (int ni = 0; ni < NHALF; ni++)
          #pragma unroll
          for (int kk = 0; kk < 2; kk++)
            acc[m * 2 + mi][n2 * NHALF + ni] =
                mfma16(af[mi][kk], bfr[n2][ni][kk], acc[m * 2 + mi][n2 * NHALF + ni]);
      __builtin_amdgcn_s_setprio(0);
      __builtin_amdgcn_sched_barrier(0);
      __builtin_amdgcn_s_barrier();
    }
  }

  #pragma unroll
  for (int a = 0; a < 4; a++) {
    #pragma unroll
    for (int j = 0; j < N_REP; j++) {
      int row0 = m0 + wr * 64 + (a >> 1) * 32 + (a & 1) * 16 + kg * 4;
      int col = n0 + wcn * (16 * N_REP) + j * 16 + ql;
      #pragma unroll
      for (int r = 0; r < 4; r++) {
        if constexpr (OUT_BF16)
          Cb[(size_t)(row0 + r) * N + col] = f2bf(acc[a][j][r]);
        else
          Cf[(size_t)(row0 + r) * N + col] = acc[a][j][r];
      }
    }
  }
}

// ---------------- flash attention, causal, GQA (g=4) ----------------
// (unchanged from R9/R12)
__global__ __launch_bounds__(256, 2)
void attn_k(const u16* __restrict__ qr, const u16* __restrict__ kr,
            const u16* __restrict__ qkv, u16* __restrict__ out) {
  __shared__ alignas(16) u16 Kls[2][64 * 128];
  __shared__ alignas(16) u16 Vt[2][128][72];
  __shared__ alignas(16) u16 Plds[4][16][72];
  const int tid = threadIdx.x;
  const int lane = tid & 63, wave = tid >> 6;
  const int ql = lane & 15, kg = lane >> 4;
  const int h = blockIdx.y, hk = h >> 2;

  const int sl4 = (tid & 15) * 4;
  const int d0s = (tid >> 4) * 8;
  const u16* vbase = qkv + 5120 + (size_t)hk * 128 + d0s;
  const int krow_s = tid >> 4, kcol_s = (tid & 15) * 8;
  const u16* kbase = kr + (size_t)hk * 128 + (size_t)krow_s * 1024 + kcol_s;

  int cur = 0;
  #pragma unroll 1
  for (int half_idx = 0; half_idx < 2; half_idx++) {
    const int tile = half_idx ? (31 - (int)blockIdx.x) : (int)blockIdx.x;
    const int q0 = tile * 64;
    const int qw = q0 + wave * 16;
    const int nsteps = tile + 1;

    u16x8 qf[4];
    const u16* qbase = qr + ((size_t)(qw + ql) * 32 + h) * 128;
    #pragma unroll
    for (int kk = 0; kk < 4; kk++)
      qf[kk] = *(const u16x8*)(qbase + kk * 32 + kg * 8);

    f32x4 acc[8] = {};
    float m_run = -3e38f, l_run = 0.f;

    __syncthreads();
    cur = 0;
    #pragma unroll
    for (int r = 0; r < 4; r++)
      load_lds16(kbase + (size_t)r * 16 * 1024, &Kls[0][(r * 256 + tid) * 8]);
    u16x8 vreg[4];
    #pragma unroll
    for (int j = 0; j < 4; j++)
      vreg[j] = *(const u16x8*)(vbase + (size_t)(sl4 + j) * 6144);

    #pragma unroll 1
    for (int t = 0; t < nsteps; t++) {
      const int s0 = t * 64;
      #pragma unroll
      for (int e = 0; e < 8; e++) {
        ushort4 w;
        w.x = vreg[0][e]; w.y = vreg[1][e]; w.z = vreg[2][e]; w.w = vreg[3][e];
        *(ushort4*)&Vt[cur][d0s + e][sl4] = w;
      }
      __syncthreads();  // the ONLY barrier per step
      if (t + 1 < nsteps) {
        const u16* kn = kbase + (size_t)(s0 + 64) * 1024;
        #pragma unroll
        for (int r = 0; r < 4; r++)
          load_lds16(kn + (size_t)r * 16 * 1024, &Kls[cur ^ 1][(r * 256 + tid) * 8]);
        #pragma unroll
        for (int j = 0; j < 4; j++)
          vreg[j] = *(const u16x8*)(vbase + (size_t)(s0 + 64 + sl4 + j) * 6144);
      }
      f32x4 sc[4] = {};
      __builtin_amdgcn_s_setprio(1);
      #pragma unroll
      for (int sb = 0; sb < 4; sb++) {
        const u16* krow = &Kls[cur][(sb * 16 + ql) * 128];
        #pragma unroll
        for (int kk = 0; kk < 4; kk++) {
          u16x8 kf = *(const u16x8*)(krow + (((kk * 4 + kg) ^ (ql & 7)) * 8));
          sc[sb] = mfma16(kf, qf[kk], sc[sb]);
        }
      }
      __builtin_amdgcn_s_setprio(0);
      const int qg = qw + ql;
      float mt = -3e38f;
      #pragma unroll
      for (int sb = 0; sb < 4; sb++)
        #pragma unroll
        for (int r = 0; r < 4; r++) {
          int s = s0 + sb * 16 + kg * 4 + r;
          float v = (s > qg) ? -3e38f : sc[sb][r];
          sc[sb][r] = v;
          mt = fmaxf(mt, v);
        }
      mt = fmaxf(mt, __shfl_xor(mt, 16, 64));
      mt = fmaxf(mt, __shfl_xor(mt, 32, 64));
      if (!__all(mt - m_run <= 11.5f)) {
        float m_new = fmaxf(m_run, mt);
        float fco = exp2f(m_run - m_new);
        float fr[4];
        #pragma unroll
        for (int r = 0; r < 4; r++) fr[r] = __shfl(fco, (lane & 48) | (kg * 4 + r), 64);
        #pragma unroll
        for (int db = 0; db < 8; db++)
          #pragma unroll
          for (int r = 0; r < 4; r++) acc[db][r] *= fr[r];
        l_run *= fco;
        m_run = m_new;
      }
      float rs = 0.f;
      #pragma unroll
      for (int sb = 0; sb < 4; sb++)
        #pragma unroll
        for (int r = 0; r < 4; r++) {
          float e = exp2f(sc[sb][r] - m_run);
          sc[sb][r] = e;
          rs += e;
        }
      rs += __shfl_xor(rs, 16, 64);
      rs += __shfl_xor(rs, 32, 64);
      l_run += rs;
      #pragma unroll
      for (int sb = 0; sb < 4; sb++) {
        ushort4 pk;
        pk.x = f2bf(sc[sb][0]); pk.y = f2bf(sc[sb][1]);
        pk.z = f2bf(sc[sb][2]); pk.w = f2bf(sc[sb][3]);
        *(ushort4*)&Plds[wave][ql][sb * 16 + kg * 4] = pk;
      }
      __builtin_amdgcn_s_setprio(1);
      #pragma unroll
      for (int hf = 0; hf < 2; hf++) {
        u16x8 pf = *(const u16x8*)&Plds[wave][ql][hf * 32 + kg * 8];
        #pragma unroll
        for (int db = 0; db < 8; db++) {
          u16x8 vf = *(const u16x8*)&Vt[cur][db * 16 + ql][hf * 32 + kg * 8];
          acc[db] = mfma16(pf, vf, acc[db]);
        }
      }
      __builtin_amdgcn_s_setprio(0);
      cur ^= 1;
    }

    float linv[4];
    #pragma unroll
    for (int r = 0; r < 4; r++)
      linv[r] = 1.f / __shfl(l_run, (lane & 48) | (kg * 4 + r), 64);
    #pragma unroll
    for (int db = 0; db < 8; db++) {
      int d = db * 16 + ql;
      #pragma unroll
      for (int r = 0; r < 4; r++) {
        int q = qw + kg * 4 + r;
        int col = (h * 128 + d) ^ ((q & 7) << 3);
        out[(size_t)q * 4096 + col] = f2bf(acc[db][r] * linv[r]);
      }
    }
  }
}

// ---------------- launcher ----------------
extern "C" void kernel_launch(void* const* d_in, const int* in_sizes, int n_in,
                              void* d_out, int out_size, void* d_ws, size_t ws_size,
                              hipStream_t stream) {
  const float* x  = (const float*)d_in[0];
  const float* Wq = (const float*)d_in[1];
  const float* Wk = (const float*)d_in[2];
  const float* Wv = (const float*)d_in[3];
  const float* Wo = (const float*)d_in[4];
  const int* start = (const int*)d_in[5];

  const int L = 2048, HID = 4096, NH = 32, NKV = 8;
  const int NQ = 4096, NKVD = 1024, NF = 6144;

  char* ws = (char*)d_ws;
  size_t off = 0;
  auto alloc = [&](size_t bytes) {
    void* p = ws + off;
    off += (bytes + 255) & ~(size_t)255;
    return p;
  };
  u16* x_b   = (u16*)alloc((size_t)L * HID * 2);
  // Wq_t, Wk_t, Wv_t MUST be contiguous (fused GEMM reads them as one 6144-row Bt).
  u16* Wq_t  = (u16*)alloc((size_t)NQ * HID * 2);
  u16* Wk_t  = (u16*)alloc((size_t)NKVD * HID * 2);
  u16* Wv_t  = (u16*)alloc((size_t)NKVD * HID * 2);
  u16* Wo_t  = (u16*)alloc((size_t)HID * NQ * 2);
  u16* q_r   = (u16*)alloc((size_t)L * NQ * 2);
  u16* k_r   = (u16*)alloc((size_t)L * NKVD * 2);
  float2* tab = (float2*)alloc((size_t)L * 64 * sizeof(float2));
  u16* qkv_b  = (u16*)d_out;   // fused QKV output; fully rewritten by out-proj
  u16* attn_b = Wq_t;          // reuse Wq^T region after the fused GEMM

  const float qscale = 0.08838834764831845f * 1.4426950408889634f;  // 1/sqrt(128)*log2(e)

  // conversions / transposes / table (all GEMM inputs pre-swizzled)
  cvt_f32_bf16_swz<<<(L * HID / 8 + 255) / 256, 256, 0, stream>>>(x, x_b, L * HID / 8);
  transpose_cvt<<<dim3(HID / 128, NQ / 32), 256, 0, stream>>>(Wq, Wq_t, HID, NQ);
  transpose_cvt<<<dim3(HID / 128, NKVD / 32), 256, 0, stream>>>(Wk, Wk_t, HID, NKVD);
  transpose_cvt<<<dim3(HID / 128, NKVD / 32), 256, 0, stream>>>(Wv, Wv_t, HID, NKVD);
  transpose_cvt<<<dim3(NQ / 128, HID / 32), 256, 0, stream>>>(Wo, Wo_t, NQ, HID);
  rope_table_k<<<(L * 64 + 255) / 256, 256, 0, stream>>>(tab, start, L);

  // fused QKV projection: BM=128 x BN=192 tiles, grid 16x32 = 512 (2 blocks/CU)
  gemm8p<192, true><<<512, 256, 0, stream>>>(x_b, Wq_t, nullptr, qkv_b, NF, HID, 16);

  // RoPE: Q (scaled, log2e folded, linear) and K (unscaled, chunk-swizzled)
  rope_apply_b<<<(L * NH * 8 + 255) / 256, 256, 0, stream>>>(qkv_b, NF, 0, q_r, tab, L * NH * 8, NH, qscale, 0);
  rope_apply_b<<<(L * NKV * 8 + 255) / 256, 256, 0, stream>>>(qkv_b, NF, NQ, k_r, tab, L * NKV * 8, NKV, 1.0f, 1);

  // attention
  attn_k<<<dim3(16, NH), 256, 0, stream>>>(q_r, k_r, qkv_b, attn_b);

  // output projection: BM=128 x BN=128 tiles, grid 16x32 = 512 (2 blocks/CU)
  gemm8p<128, false><<<512, 256, 0, stream>>>(attn_b, Wo_t, (float*)d_out, nullptr, HID, NQ, 16);
}